// Round 3
// baseline (207.812 us; speedup 1.0000x reference)
//
#include <hip/hip_runtime.h>
#include <hip/hip_bf16.h>

namespace {
constexpr int N = 16384;
constexpr int K = 2048;
constexpr int D = 1000;
constexpr int DP = 1024;           // padded reduction dim
constexpr size_t ND = (size_t)N * D;
constexpr float WSCALE = 1024.0f;  // codebook pre-scale so fp8 doesn't underflow

// workspace layout
constexpr size_t OFF_BEST   = 0;                               // N * u64
constexpr size_t OFF_COUNTS = OFF_BEST + (size_t)N * 8;        // K * u32
constexpr size_t HDR_BYTES  = OFF_COUNTS + (size_t)K * 4;      // memset region (best+counts)
constexpr size_t OFF_PART   = HDR_BYTES;                       // 2048*2 f32
constexpr size_t OFF_XQ     = OFF_PART + 2048 * 2 * 4;         // N*DP fp8
constexpr size_t OFF_WQ     = OFF_XQ + (size_t)N * DP;         // K*DP fp8
constexpr size_t OFF_WNORM  = OFF_WQ + (size_t)K * DP;         // K f32
}

typedef __attribute__((ext_vector_type(8))) int int8v;
typedef __attribute__((ext_vector_type(4))) float f32x4;

typedef const __attribute__((address_space(1))) unsigned int* gp_t;
typedef __attribute__((address_space(3))) unsigned int* lp_t;

// fp32 [rows][1000] -> fp8 e4m3 [rows][1024] (zero padded), optional pre-scale
__global__ __launch_bounds__(256) void conv_fp8_kernel(const float* __restrict__ src,
                                                       unsigned char* __restrict__ dst,
                                                       int nrows, float scale) {
  int t = blockIdx.x * 256 + threadIdx.x;
  int r = t >> 7;          // 128 chunks of 8 elements per row
  int c = t & 127;
  if (r >= nrows) return;
  int w0 = 0, w1 = 0;
  if (c < 125) {           // 125*8 = 1000 exactly
    const float* p = src + (size_t)r * D + (c << 3);
    float4 v0 = *reinterpret_cast<const float4*>(p);
    float4 v1 = *reinterpret_cast<const float4*>(p + 4);
    w0 = __builtin_amdgcn_cvt_pk_fp8_f32(v0.x * scale, v0.y * scale, w0, false);
    w0 = __builtin_amdgcn_cvt_pk_fp8_f32(v0.z * scale, v0.w * scale, w0, true);
    w1 = __builtin_amdgcn_cvt_pk_fp8_f32(v1.x * scale, v1.y * scale, w1, false);
    w1 = __builtin_amdgcn_cvt_pk_fp8_f32(v1.z * scale, v1.w * scale, w1, true);
  }
  uint2 out = make_uint2((unsigned)w0, (unsigned)w1);
  *reinterpret_cast<uint2*>(dst + (size_t)r * DP + (c << 3)) = out;
}

// |w_k|^2 in fp32 from the original embedding; one wave per row
__global__ __launch_bounds__(256) void wnorm_kernel(const float* __restrict__ W,
                                                    float* __restrict__ wnorm) {
  int wv = (blockIdx.x * 256 + threadIdx.x) >> 6;
  int lane = threadIdx.x & 63;
  if (wv >= K) return;
  const float* p = W + (size_t)wv * D;
  float s = 0.f;
  for (int d = lane; d < D; d += 64) { float v = p[d]; s += v * v; }
  #pragma unroll
  for (int off = 32; off; off >>= 1) s += __shfl_down(s, off);
  if (lane == 0) wnorm[wv] = s;
}

__global__ __launch_bounds__(256) void hist_kernel(const int* __restrict__ label,
                                                   unsigned int* __restrict__ counts) {
  int t = blockIdx.x * 256 + threadIdx.x;
  if (t < N) atomicAdd(&counts[label[t]], 1u);
}

// encodings = one_hot(label); float2 stores (base offset is only 8B-aligned)
__global__ __launch_bounds__(256) void encodings_kernel(const int* __restrict__ label,
                                                        float2* __restrict__ enc) {
  size_t t = (size_t)blockIdx.x * 256 + threadIdx.x;   // N*K/2 threads
  int row = (int)(t >> 10);                            // K/2 = 1024 float2 per row
  int c2 = (int)(t & 1023);
  int lab = label[row];
  float2 v = make_float2(0.f, 0.f);
  if ((lab >> 1) == c2) { if (lab & 1) v.y = 1.f; else v.x = 1.f; }
  enc[t] = v;
}

// score[n][k] = 2*x_n.w_k - |w_k|^2 via MX-fp8 K=128 MFMA, 128x128 tile, 2-phase.
// A,B staged linear in LDS via global_load_lds(16B). Wq is pre-scaled by 1024;
// epilogue multiplies the dot by 2/1024.
// pack = (orderable(score) << 32) | ~col  -> atomicMax == (max score, min col)
__global__ __launch_bounds__(256) void argmin_kernel(const unsigned char* __restrict__ Xq,
                                                     const unsigned char* __restrict__ Wq,
                                                     const float* __restrict__ wnorm,
                                                     unsigned long long* __restrict__ best) {
  constexpr int BKB = 128;   // k-bytes per step (fp8, K=128)
  __shared__ __attribute__((aligned(32))) unsigned char Asm[128 * BKB];  // 16 KB
  __shared__ __attribute__((aligned(32))) unsigned char Bsm[128 * BKB];  // 16 KB

  const int tid = threadIdx.x;
  const int w = tid >> 6, l = tid & 63;
  const int wr = w >> 1, wc = w & 1;
  const int lr = l & 15, lhk = l >> 4;
  const int r0 = blockIdx.x * 128;
  const int c0 = blockIdx.y * 128;

  // staging: thread t covers row t>>3 (+32 per issue), 16 fp8 bytes at col (t&7)*16.
  const int srow = tid >> 3;
  const int scolb = (tid & 7) * 16;
  const unsigned char* gA = Xq + (size_t)(r0 + srow) * DP + scolb;
  const unsigned char* gB = Wq + (size_t)(c0 + srow) * DP + scolb;
  auto asA = (__attribute__((address_space(3))) unsigned char*)Asm;
  auto asB = (__attribute__((address_space(3))) unsigned char*)Bsm;
  const int wbase = w * 1024;              // bytes: wave's 64 lanes x 16B

  f32x4 zero = {0.f, 0.f, 0.f, 0.f};
  f32x4 acc[4][4];
  #pragma unroll
  for (int m = 0; m < 4; ++m)
    #pragma unroll
    for (int n = 0; n < 4; ++n) acc[m][n] = zero;

  // fragment LDS byte offsets: row = (sub*64 + m*16 + lr), k-bytes = lhk*32..+32
  int aoff[4], boff[4];
  #pragma unroll
  for (int m = 0; m < 4; ++m) {
    aoff[m] = (wr * 64 + m * 16 + lr) * BKB + lhk * 32;
    boff[m] = (wc * 64 + m * 16 + lr) * BKB + lhk * 32;
  }

  // prologue stage k0=0: 4 issues x (A,B), 32 rows per issue
  #pragma unroll
  for (int i = 0; i < 4; ++i) {
    __builtin_amdgcn_global_load_lds((gp_t)(gA + (size_t)(32 * i) * DP),
                                     (lp_t)(asA + i * 4096 + wbase), 16, 0, 0);
    __builtin_amdgcn_global_load_lds((gp_t)(gB + (size_t)(32 * i) * DP),
                                     (lp_t)(asB + i * 4096 + wbase), 16, 0, 0);
  }

  for (int k0 = 0; k0 < DP; k0 += BKB) {
    __syncthreads();   // drains vmcnt -> staged LDS visible
    int8v a[4], b[4];
    #pragma unroll
    for (int m = 0; m < 4; ++m) {
      a[m] = *reinterpret_cast<const int8v*>(Asm + aoff[m]);
      b[m] = *reinterpret_cast<const int8v*>(Bsm + boff[m]);
    }
    #pragma unroll
    for (int m = 0; m < 4; ++m)
      #pragma unroll
      for (int n = 0; n < 4; ++n)
        acc[m][n] = __builtin_amdgcn_mfma_scale_f32_16x16x128_f8f6f4(
            a[m], b[n], acc[m][n], 0, 0, 0, 0x7f7f7f7f, 0, 0x7f7f7f7f);
    if (k0 + BKB < DP) {
      __syncthreads();  // all waves done reading before restage
      const int k1 = k0 + BKB;
      #pragma unroll
      for (int i = 0; i < 4; ++i) {
        __builtin_amdgcn_global_load_lds((gp_t)(gA + k1 + (size_t)(32 * i) * DP),
                                         (lp_t)(asA + i * 4096 + wbase), 16, 0, 0);
        __builtin_amdgcn_global_load_lds((gp_t)(gB + k1 + (size_t)(32 * i) * DP),
                                         (lp_t)(asB + i * 4096 + wbase), 16, 0, 0);
      }
    }
  }

  // epilogue: scores + per-row argmax
  float wn[4];
  #pragma unroll
  for (int n = 0; n < 4; ++n) wn[n] = wnorm[c0 + wc * 64 + n * 16 + lr];
  const float dsc = 2.0f / WSCALE;

  #pragma unroll
  for (int m = 0; m < 4; ++m) {
    #pragma unroll
    for (int t = 0; t < 4; ++t) {
      const int row = r0 + wr * 64 + m * 16 + lhk * 4 + t;
      unsigned long long pk = 0ull;
      #pragma unroll
      for (int n = 0; n < 4; ++n) {
        const int col = c0 + wc * 64 + n * 16 + lr;
        float score = dsc * acc[m][n][t] - wn[n];
        unsigned int u = __float_as_uint(score);
        u = (u & 0x80000000u) ? ~u : (u | 0x80000000u);
        unsigned long long p = ((unsigned long long)u << 32) | (unsigned int)(~col);
        if (p > pk) pk = p;
      }
      #pragma unroll
      for (int off = 1; off < 16; off <<= 1) {
        unsigned long long o = __shfl_xor(pk, off);
        if (o > pk) pk = o;
      }
      if (lr == 0) atomicMax(best + row, pk);
    }
  }
}

// gather quantized rows, write straight-through output, per-block partial sums (NO atomics)
__global__ __launch_bounds__(256) void gather_loss_kernel(const float* __restrict__ X,
                                                          const float* __restrict__ W,
                                                          const int* __restrict__ label,
                                                          const unsigned long long* __restrict__ best,
                                                          float* __restrict__ outq,
                                                          float* __restrict__ partials) {
  const int tid = threadIdx.x;
  float qs = 0.f, xs = 0.f;
  #pragma unroll
  for (int i = 0; i < 8; ++i) {
    const int r = blockIdx.x * 8 + i;
    const int lab = label[r];
    const int k = (int)(~(unsigned int)(best[r] & 0xffffffffull));
    const float ind = (lab != k) ? 1.0f : 0.0f;
    if (tid < 250) {
      const float4 x4 = reinterpret_cast<const float4*>(X + (size_t)r * D)[tid];
      const float4 q4 = reinterpret_cast<const float4*>(W + (size_t)lab * D)[tid];
      const float4 c4 = reinterpret_cast<const float4*>(W + (size_t)k * D)[tid];
      float* orow = outq + (size_t)r * D + tid * 4;
      orow[0] = x4.x + (q4.x - x4.x);
      orow[1] = x4.y + (q4.y - x4.y);
      orow[2] = x4.z + (q4.z - x4.z);
      orow[3] = x4.w + (q4.w - x4.w);
      float dq, dc, rx = 0.f, rq = 0.f;
      dq = q4.x - x4.x; rq += dq * dq;  dq = q4.y - x4.y; rq += dq * dq;
      dq = q4.z - x4.z; rq += dq * dq;  dq = q4.w - x4.w; rq += dq * dq;
      dc = c4.x - x4.x; rx += dc * dc;  dc = c4.y - x4.y; rx += dc * dc;
      dc = c4.z - x4.z; rx += dc * dc;  dc = c4.w - x4.w; rx += dc * dc;
      qs += rq;
      xs += ind * rx;
    }
  }
  #pragma unroll
  for (int off = 32; off; off >>= 1) {
    qs += __shfl_down(qs, off);
    xs += __shfl_down(xs, off);
  }
  __shared__ float sq[4], sx[4];
  if ((tid & 63) == 0) { sq[tid >> 6] = qs; sx[tid >> 6] = xs; }
  __syncthreads();
  if (tid == 0) {
    partials[blockIdx.x * 2 + 0] = sq[0] + sq[1] + sq[2] + sq[3];
    partials[blockIdx.x * 2 + 1] = sx[0] + sx[1] + sx[2] + sx[3];
  }
}

__global__ __launch_bounds__(256) void final_kernel(const unsigned int* __restrict__ counts,
                                                    const float* __restrict__ partials,
                                                    float* __restrict__ out) {
  const int tid = threadIdx.x;
  float e = 0.f, qs = 0.f, xs = 0.f;
  for (int k = tid; k < K; k += 256) {
    float p = (float)counts[k] * (1.0f / (float)N);
    e += p * logf(p + 1e-10f);
  }
  for (int i = tid; i < 2048; i += 256) {
    qs += partials[i * 2 + 0];
    xs += partials[i * 2 + 1];
  }
  #pragma unroll
  for (int off = 32; off; off >>= 1) {
    e += __shfl_down(e, off);
    qs += __shfl_down(qs, off);
    xs += __shfl_down(xs, off);
  }
  __shared__ float se[4], ssq[4], ssx[4];
  if ((tid & 63) == 0) { se[tid >> 6] = e; ssq[tid >> 6] = qs; ssx[tid >> 6] = xs; }
  __syncthreads();
  if (tid == 0) {
    float ent = se[0] + se[1] + se[2] + se[3];
    float q = ssq[0] + ssq[1] + ssq[2] + ssq[3];
    float x = ssx[0] + ssx[1] + ssx[2] + ssx[3];
    const float inv = 1.0f / (float)((long long)N * D);
    out[0] = 1.25f * q * inv - 1.1f * x * inv;   // loss
    out[1 + ND] = expf(-ent);                    // perplexity
  }
}

extern "C" void kernel_launch(void* const* d_in, const int* in_sizes, int n_in,
                              void* d_out, int out_size, void* d_ws, size_t ws_size,
                              hipStream_t stream) {
  const float* X = (const float*)d_in[0];
  const int* label = (const int*)d_in[1];
  const float* W = (const float*)d_in[2];
  float* out = (float*)d_out;
  char* ws = (char*)d_ws;

  unsigned long long* best = (unsigned long long*)(ws + OFF_BEST);
  unsigned int* counts = (unsigned int*)(ws + OFF_COUNTS);
  float* partials = (float*)(ws + OFF_PART);
  unsigned char* Xq = (unsigned char*)(ws + OFF_XQ);
  unsigned char* Wq = (unsigned char*)(ws + OFF_WQ);
  float* wnorm = (float*)(ws + OFF_WNORM);

  hipMemsetAsync(d_ws, 0, HDR_BYTES, stream);

  conv_fp8_kernel<<<(N * 128) / 256, 256, 0, stream>>>(X, Xq, N, 1.0f);
  conv_fp8_kernel<<<(K * 128) / 256, 256, 0, stream>>>(W, Wq, K, WSCALE);
  wnorm_kernel<<<K / 4, 256, 0, stream>>>(W, wnorm);
  hist_kernel<<<N / 256, 256, 0, stream>>>(label, counts);
  encodings_kernel<<<(int)((size_t)N * K / 2 / 256), 256, 0, stream>>>(
      label, (float2*)(out + 2 + ND));
  argmin_kernel<<<dim3(N / 128, K / 128), 256, 0, stream>>>(Xq, Wq, wnorm, best);
  gather_loss_kernel<<<N / 8, 256, 0, stream>>>(X, W, label, best, out + 1, partials);
  final_kernel<<<1, 256, 0, stream>>>(counts, partials, out);
}

// Round 4
// 195.875 us; speedup vs baseline: 1.0609x; 1.0609x over previous
//
#include <hip/hip_runtime.h>
#include <hip/hip_bf16.h>

namespace {
constexpr int N = 16384;
constexpr int K = 2048;
constexpr int D = 1000;
constexpr int DP = 1024;           // padded reduction dim
constexpr size_t ND = (size_t)N * D;
constexpr float WSCALE = 1024.0f;  // codebook pre-scale so fp8 doesn't underflow

// workspace layout
constexpr size_t OFF_BEST   = 0;                               // N * u64
constexpr size_t OFF_COUNTS = OFF_BEST + (size_t)N * 8;        // K * u32
constexpr size_t HDR_BYTES  = OFF_COUNTS + (size_t)K * 4;      // memset region (best+counts)
constexpr size_t OFF_PART   = HDR_BYTES;                       // 2048*2 f32
constexpr size_t OFF_XQ     = OFF_PART + 2048 * 2 * 4;         // N*DP fp8
constexpr size_t OFF_WQ     = OFF_XQ + (size_t)N * DP;         // K*DP fp8
constexpr size_t OFF_WNORM  = OFF_WQ + (size_t)K * DP;         // K f32
}

typedef __attribute__((ext_vector_type(8))) int int8v;
typedef __attribute__((ext_vector_type(4))) int int4v;
typedef __attribute__((ext_vector_type(4))) float f32x4;

typedef const __attribute__((address_space(1))) unsigned int* gp_t;
typedef __attribute__((address_space(3))) unsigned int* lp_t;

// fp32 [rows][1000] -> fp8 e4m3 [rows][1024] (zero padded), optional pre-scale
__global__ __launch_bounds__(256) void conv_fp8_kernel(const float* __restrict__ src,
                                                       unsigned char* __restrict__ dst,
                                                       int nrows, float scale) {
  int t = blockIdx.x * 256 + threadIdx.x;
  int r = t >> 7;          // 128 chunks of 8 elements per row
  int c = t & 127;
  if (r >= nrows) return;
  int w0 = 0, w1 = 0;
  if (c < 125) {           // 125*8 = 1000 exactly
    const float* p = src + (size_t)r * D + (c << 3);
    float4 v0 = *reinterpret_cast<const float4*>(p);
    float4 v1 = *reinterpret_cast<const float4*>(p + 4);
    w0 = __builtin_amdgcn_cvt_pk_fp8_f32(v0.x * scale, v0.y * scale, w0, false);
    w0 = __builtin_amdgcn_cvt_pk_fp8_f32(v0.z * scale, v0.w * scale, w0, true);
    w1 = __builtin_amdgcn_cvt_pk_fp8_f32(v1.x * scale, v1.y * scale, w1, false);
    w1 = __builtin_amdgcn_cvt_pk_fp8_f32(v1.z * scale, v1.w * scale, w1, true);
  }
  uint2 out = make_uint2((unsigned)w0, (unsigned)w1);
  *reinterpret_cast<uint2*>(dst + (size_t)r * DP + (c << 3)) = out;
}

// |w_k|^2 in fp32 from the original embedding; one wave per row
__global__ __launch_bounds__(256) void wnorm_kernel(const float* __restrict__ W,
                                                    float* __restrict__ wnorm) {
  int wv = (blockIdx.x * 256 + threadIdx.x) >> 6;
  int lane = threadIdx.x & 63;
  if (wv >= K) return;
  const float* p = W + (size_t)wv * D;
  float s = 0.f;
  for (int d = lane; d < D; d += 64) { float v = p[d]; s += v * v; }
  #pragma unroll
  for (int off = 32; off; off >>= 1) s += __shfl_down(s, off);
  if (lane == 0) wnorm[wv] = s;
}

__global__ __launch_bounds__(256) void hist_kernel(const int* __restrict__ label,
                                                   unsigned int* __restrict__ counts) {
  int t = blockIdx.x * 256 + threadIdx.x;
  if (t < N) atomicAdd(&counts[label[t]], 1u);
}

// encodings = one_hot(label); float2 stores (base offset is only 8B-aligned)
__global__ __launch_bounds__(256) void encodings_kernel(const int* __restrict__ label,
                                                        float2* __restrict__ enc) {
  size_t t = (size_t)blockIdx.x * 256 + threadIdx.x;   // N*K/2 threads
  int row = (int)(t >> 10);                            // K/2 = 1024 float2 per row
  int c2 = (int)(t & 1023);
  int lab = label[row];
  float2 v = make_float2(0.f, 0.f);
  if ((lab >> 1) == c2) { if (lab & 1) v.y = 1.f; else v.x = 1.f; }
  enc[t] = v;
}

// score[n][k] = 2*x_n.w_k - |w_k|^2 via MX-fp8 K=128 MFMA, 128x128 tile.
// T2 both-sides swizzle: LDS linear (global_load_lds), global SOURCE chunk
// pre-swizzled by (row&7), ds_read applies the same XOR (rule #21 involution).
// Raw s_barrier + manual waitcnt so next-tile stage loads fly under the MFMAs.
// pack = (orderable(score) << 32) | ~col  -> atomicMax == (max score, min col)
__global__ __launch_bounds__(256) void argmin_kernel(const unsigned char* __restrict__ Xq,
                                                     const unsigned char* __restrict__ Wq,
                                                     const float* __restrict__ wnorm,
                                                     unsigned long long* __restrict__ best) {
  constexpr int BKB = 128;   // k-bytes per step (fp8, K=128)
  __shared__ __attribute__((aligned(32))) unsigned char Asm[128 * BKB];  // 16 KB
  __shared__ __attribute__((aligned(32))) unsigned char Bsm[128 * BKB];  // 16 KB

  const int tid = threadIdx.x;
  const int w = tid >> 6, l = tid & 63;
  const int wr = w >> 1, wc = w & 1;
  const int lr = l & 15, lhk = l >> 4;
  const int r0 = blockIdx.x * 128;
  const int c0 = blockIdx.y * 128;

  // staging: thread t covers LDS row tid>>3 (+32 per issue), chunk tid&7 (16 B).
  // source chunk pre-swizzled: c ^ (row&7); (row&7) == ((tid>>3)&7) for all issues.
  const int srow = tid >> 3;
  const int scolb = (((tid & 7) ^ ((tid >> 3) & 7)) << 4);
  const unsigned char* gA = Xq + (size_t)(r0 + srow) * DP + scolb;
  const unsigned char* gB = Wq + (size_t)(c0 + srow) * DP + scolb;
  auto asA = (__attribute__((address_space(3))) unsigned char*)Asm;
  auto asB = (__attribute__((address_space(3))) unsigned char*)Bsm;
  const int wbase = w * 1024;              // bytes: wave's 64 lanes x 16B

  f32x4 zero = {0.f, 0.f, 0.f, 0.f};
  f32x4 acc[4][4];
  #pragma unroll
  for (int m = 0; m < 4; ++m)
    #pragma unroll
    for (int n = 0; n < 4; ++n) acc[m][n] = zero;

  // swizzled fragment LDS byte offsets: row r, k-chunks {2*lhk, 2*lhk+1} ^ (r&7)
  const int s = lr & 7;
  const int j0 = lhk * 2;
  int aoff_lo[4], aoff_hi[4], boff_lo[4], boff_hi[4];
  #pragma unroll
  for (int m = 0; m < 4; ++m) {
    const int ra = wr * 64 + m * 16 + lr;
    const int rb = wc * 64 + m * 16 + lr;
    aoff_lo[m] = ra * BKB + ((j0 ^ s) << 4);
    aoff_hi[m] = ra * BKB + (((j0 + 1) ^ s) << 4);
    boff_lo[m] = rb * BKB + ((j0 ^ s) << 4);
    boff_hi[m] = rb * BKB + (((j0 + 1) ^ s) << 4);
  }

  // prologue stage k0=0: 4 issues x (A,B), 32 rows per issue
  #pragma unroll
  for (int i = 0; i < 4; ++i) {
    __builtin_amdgcn_global_load_lds((gp_t)(gA + (size_t)(32 * i) * DP),
                                     (lp_t)(asA + i * 4096 + wbase), 16, 0, 0);
    __builtin_amdgcn_global_load_lds((gp_t)(gB + (size_t)(32 * i) * DP),
                                     (lp_t)(asB + i * 4096 + wbase), 16, 0, 0);
  }

  for (int k0 = 0; k0 < DP; k0 += BKB) {
    asm volatile("s_waitcnt vmcnt(0)" ::: "memory");  // my stage loads landed
    __builtin_amdgcn_s_barrier();                     // everyone's landed -> tile ready
    int8v a[4], b[4];
    #pragma unroll
    for (int m = 0; m < 4; ++m) {
      int4v alo = *reinterpret_cast<const int4v*>(Asm + aoff_lo[m]);
      int4v ahi = *reinterpret_cast<const int4v*>(Asm + aoff_hi[m]);
      int4v blo = *reinterpret_cast<const int4v*>(Bsm + boff_lo[m]);
      int4v bhi = *reinterpret_cast<const int4v*>(Bsm + boff_hi[m]);
      a[m][0] = alo[0]; a[m][1] = alo[1]; a[m][2] = alo[2]; a[m][3] = alo[3];
      a[m][4] = ahi[0]; a[m][5] = ahi[1]; a[m][6] = ahi[2]; a[m][7] = ahi[3];
      b[m][0] = blo[0]; b[m][1] = blo[1]; b[m][2] = blo[2]; b[m][3] = blo[3];
      b[m][4] = bhi[0]; b[m][5] = bhi[1]; b[m][6] = bhi[2]; b[m][7] = bhi[3];
    }
    asm volatile("s_waitcnt lgkmcnt(0)" ::: "memory"); // my ds_reads complete
    __builtin_amdgcn_s_barrier();                      // all waves done reading
    __builtin_amdgcn_sched_barrier(0);                 // pin stage issue here
    if (k0 + BKB < DP) {
      const int k1 = k0 + BKB;
      #pragma unroll
      for (int i = 0; i < 4; ++i) {
        __builtin_amdgcn_global_load_lds((gp_t)(gA + k1 + (size_t)(32 * i) * DP),
                                         (lp_t)(asA + i * 4096 + wbase), 16, 0, 0);
        __builtin_amdgcn_global_load_lds((gp_t)(gB + k1 + (size_t)(32 * i) * DP),
                                         (lp_t)(asB + i * 4096 + wbase), 16, 0, 0);
      }
    }
    #pragma unroll
    for (int m = 0; m < 4; ++m)
      #pragma unroll
      for (int n = 0; n < 4; ++n)
        acc[m][n] = __builtin_amdgcn_mfma_scale_f32_16x16x128_f8f6f4(
            a[m], b[n], acc[m][n], 0, 0, 0, 0x7f7f7f7f, 0, 0x7f7f7f7f);
  }

  // epilogue: scores + per-row argmax
  float wn[4];
  #pragma unroll
  for (int n = 0; n < 4; ++n) wn[n] = wnorm[c0 + wc * 64 + n * 16 + lr];
  const float dsc = 2.0f / WSCALE;

  #pragma unroll
  for (int m = 0; m < 4; ++m) {
    #pragma unroll
    for (int t = 0; t < 4; ++t) {
      const int row = r0 + wr * 64 + m * 16 + lhk * 4 + t;
      unsigned long long pk = 0ull;
      #pragma unroll
      for (int n = 0; n < 4; ++n) {
        const int col = c0 + wc * 64 + n * 16 + lr;
        float score = dsc * acc[m][n][t] - wn[n];
        unsigned int u = __float_as_uint(score);
        u = (u & 0x80000000u) ? ~u : (u | 0x80000000u);
        unsigned long long p = ((unsigned long long)u << 32) | (unsigned int)(~col);
        if (p > pk) pk = p;
      }
      #pragma unroll
      for (int off = 1; off < 16; off <<= 1) {
        unsigned long long o = __shfl_xor(pk, off);
        if (o > pk) pk = o;
      }
      if (lr == 0) atomicMax(best + row, pk);
    }
  }
}

// gather quantized rows, write straight-through output, per-block partial sums (NO atomics)
__global__ __launch_bounds__(256) void gather_loss_kernel(const float* __restrict__ X,
                                                          const float* __restrict__ W,
                                                          const int* __restrict__ label,
                                                          const unsigned long long* __restrict__ best,
                                                          float* __restrict__ outq,
                                                          float* __restrict__ partials) {
  const int tid = threadIdx.x;
  float qs = 0.f, xs = 0.f;
  #pragma unroll
  for (int i = 0; i < 8; ++i) {
    const int r = blockIdx.x * 8 + i;
    const int lab = label[r];
    const int k = (int)(~(unsigned int)(best[r] & 0xffffffffull));
    const float ind = (lab != k) ? 1.0f : 0.0f;
    if (tid < 250) {
      const float4 x4 = reinterpret_cast<const float4*>(X + (size_t)r * D)[tid];
      const float4 q4 = reinterpret_cast<const float4*>(W + (size_t)lab * D)[tid];
      const float4 c4 = reinterpret_cast<const float4*>(W + (size_t)k * D)[tid];
      float* orow = outq + (size_t)r * D + tid * 4;
      orow[0] = x4.x + (q4.x - x4.x);
      orow[1] = x4.y + (q4.y - x4.y);
      orow[2] = x4.z + (q4.z - x4.z);
      orow[3] = x4.w + (q4.w - x4.w);
      float dq, dc, rx = 0.f, rq = 0.f;
      dq = q4.x - x4.x; rq += dq * dq;  dq = q4.y - x4.y; rq += dq * dq;
      dq = q4.z - x4.z; rq += dq * dq;  dq = q4.w - x4.w; rq += dq * dq;
      dc = c4.x - x4.x; rx += dc * dc;  dc = c4.y - x4.y; rx += dc * dc;
      dc = c4.z - x4.z; rx += dc * dc;  dc = c4.w - x4.w; rx += dc * dc;
      qs += rq;
      xs += ind * rx;
    }
  }
  #pragma unroll
  for (int off = 32; off; off >>= 1) {
    qs += __shfl_down(qs, off);
    xs += __shfl_down(xs, off);
  }
  __shared__ float sq[4], sx[4];
  if ((tid & 63) == 0) { sq[tid >> 6] = qs; sx[tid >> 6] = xs; }
  __syncthreads();
  if (tid == 0) {
    partials[blockIdx.x * 2 + 0] = sq[0] + sq[1] + sq[2] + sq[3];
    partials[blockIdx.x * 2 + 1] = sx[0] + sx[1] + sx[2] + sx[3];
  }
}

__global__ __launch_bounds__(256) void final_kernel(const unsigned int* __restrict__ counts,
                                                    const float* __restrict__ partials,
                                                    float* __restrict__ out) {
  const int tid = threadIdx.x;
  float e = 0.f, qs = 0.f, xs = 0.f;
  for (int k = tid; k < K; k += 256) {
    float p = (float)counts[k] * (1.0f / (float)N);
    e += p * logf(p + 1e-10f);
  }
  for (int i = tid; i < 2048; i += 256) {
    qs += partials[i * 2 + 0];
    xs += partials[i * 2 + 1];
  }
  #pragma unroll
  for (int off = 32; off; off >>= 1) {
    e += __shfl_down(e, off);
    qs += __shfl_down(qs, off);
    xs += __shfl_down(xs, off);
  }
  __shared__ float se[4], ssq[4], ssx[4];
  if ((tid & 63) == 0) { se[tid >> 6] = e; ssq[tid >> 6] = qs; ssx[tid >> 6] = xs; }
  __syncthreads();
  if (tid == 0) {
    float ent = se[0] + se[1] + se[2] + se[3];
    float q = ssq[0] + ssq[1] + ssq[2] + ssq[3];
    float x = ssx[0] + ssx[1] + ssx[2] + ssx[3];
    const float inv = 1.0f / (float)((long long)N * D);
    out[0] = 1.25f * q * inv - 1.1f * x * inv;   // loss
    out[1 + ND] = expf(-ent);                    // perplexity
  }
}

extern "C" void kernel_launch(void* const* d_in, const int* in_sizes, int n_in,
                              void* d_out, int out_size, void* d_ws, size_t ws_size,
                              hipStream_t stream) {
  const float* X = (const float*)d_in[0];
  const int* label = (const int*)d_in[1];
  const float* W = (const float*)d_in[2];
  float* out = (float*)d_out;
  char* ws = (char*)d_ws;

  unsigned long long* best = (unsigned long long*)(ws + OFF_BEST);
  unsigned int* counts = (unsigned int*)(ws + OFF_COUNTS);
  float* partials = (float*)(ws + OFF_PART);
  unsigned char* Xq = (unsigned char*)(ws + OFF_XQ);
  unsigned char* Wq = (unsigned char*)(ws + OFF_WQ);
  float* wnorm = (float*)(ws + OFF_WNORM);

  hipMemsetAsync(d_ws, 0, HDR_BYTES, stream);

  conv_fp8_kernel<<<(N * 128) / 256, 256, 0, stream>>>(X, Xq, N, 1.0f);
  conv_fp8_kernel<<<(K * 128) / 256, 256, 0, stream>>>(W, Wq, K, WSCALE);
  wnorm_kernel<<<K / 4, 256, 0, stream>>>(W, wnorm);
  hist_kernel<<<N / 256, 256, 0, stream>>>(label, counts);
  encodings_kernel<<<(int)((size_t)N * K / 2 / 256), 256, 0, stream>>>(
      label, (float2*)(out + 2 + ND));
  argmin_kernel<<<dim3(N / 128, K / 128), 256, 0, stream>>>(Xq, Wq, wnorm, best);
  gather_loss_kernel<<<N / 8, 256, 0, stream>>>(X, W, label, best, out + 1, partials);
  final_kernel<<<1, 256, 0, stream>>>(counts, partials, out);
}

// Round 5
// 195.240 us; speedup vs baseline: 1.0644x; 1.0033x over previous
//
#include <hip/hip_runtime.h>
#include <hip/hip_bf16.h>

namespace {
constexpr int N = 16384;
constexpr int K = 2048;
constexpr int D = 1000;
constexpr int DP = 1024;           // padded reduction dim
constexpr size_t ND = (size_t)N * D;
constexpr float WSCALE = 1024.0f;  // codebook pre-scale so fp8 doesn't underflow

// workspace layout
constexpr size_t OFF_BEST   = 0;                               // N * u64
constexpr size_t OFF_COUNTS = OFF_BEST + (size_t)N * 8;        // K * u32
constexpr size_t HDR_BYTES  = OFF_COUNTS + (size_t)K * 4;      // zeroed by init_kernel
constexpr size_t OFF_PART   = HDR_BYTES;                       // 2048*2 f32
constexpr size_t OFF_XQ     = OFF_PART + 2048 * 2 * 4;         // N*DP fp8
constexpr size_t OFF_WQ     = OFF_XQ + (size_t)N * DP;         // K*DP fp8
constexpr size_t OFF_WNORM  = OFF_WQ + (size_t)K * DP;         // K f32
}

typedef __attribute__((ext_vector_type(8))) int int8v;
typedef __attribute__((ext_vector_type(4))) int int4v;
typedef __attribute__((ext_vector_type(4))) float f32x4;

typedef const __attribute__((address_space(1))) unsigned int* gp_t;
typedef __attribute__((address_space(3))) unsigned int* lp_t;

// zero best[] + counts[] (139264 B = 34 blocks * 256 threads * 16 B)
__global__ __launch_bounds__(256) void init_kernel(uint4* __restrict__ p) {
  p[blockIdx.x * 256 + threadIdx.x] = make_uint4(0u, 0u, 0u, 0u);
}

// fp32 [rows][1000] -> fp8 e4m3 [rows][1024] (zero padded), optional pre-scale
__global__ __launch_bounds__(256) void conv_fp8_kernel(const float* __restrict__ src,
                                                       unsigned char* __restrict__ dst,
                                                       int nrows, float scale) {
  int t = blockIdx.x * 256 + threadIdx.x;
  int r = t >> 7;          // 128 chunks of 8 elements per row
  int c = t & 127;
  if (r >= nrows) return;
  int w0 = 0, w1 = 0;
  if (c < 125) {           // 125*8 = 1000 exactly
    const float* p = src + (size_t)r * D + (c << 3);
    float4 v0 = *reinterpret_cast<const float4*>(p);
    float4 v1 = *reinterpret_cast<const float4*>(p + 4);
    w0 = __builtin_amdgcn_cvt_pk_fp8_f32(v0.x * scale, v0.y * scale, w0, false);
    w0 = __builtin_amdgcn_cvt_pk_fp8_f32(v0.z * scale, v0.w * scale, w0, true);
    w1 = __builtin_amdgcn_cvt_pk_fp8_f32(v1.x * scale, v1.y * scale, w1, false);
    w1 = __builtin_amdgcn_cvt_pk_fp8_f32(v1.z * scale, v1.w * scale, w1, true);
  }
  uint2 out = make_uint2((unsigned)w0, (unsigned)w1);
  *reinterpret_cast<uint2*>(dst + (size_t)r * DP + (c << 3)) = out;
}

// |w_k|^2 in fp32 from the original embedding; one wave per row
__global__ __launch_bounds__(256) void wnorm_kernel(const float* __restrict__ W,
                                                    float* __restrict__ wnorm) {
  int wv = (blockIdx.x * 256 + threadIdx.x) >> 6;
  int lane = threadIdx.x & 63;
  if (wv >= K) return;
  const float* p = W + (size_t)wv * D;
  float s = 0.f;
  for (int d = lane; d < D; d += 64) { float v = p[d]; s += v * v; }
  #pragma unroll
  for (int off = 32; off; off >>= 1) s += __shfl_down(s, off);
  if (lane == 0) wnorm[wv] = s;
}

__global__ __launch_bounds__(256) void hist_kernel(const int* __restrict__ label,
                                                   unsigned int* __restrict__ counts) {
  int t = blockIdx.x * 256 + threadIdx.x;
  if (t < N) atomicAdd(&counts[label[t]], 1u);
}

// encodings = one_hot(label); float2 stores (base offset is only 8B-aligned)
__global__ __launch_bounds__(256) void encodings_kernel(const int* __restrict__ label,
                                                        float2* __restrict__ enc) {
  size_t t = (size_t)blockIdx.x * 256 + threadIdx.x;   // N*K/2 threads
  int row = (int)(t >> 10);                            // K/2 = 1024 float2 per row
  int c2 = (int)(t & 1023);
  int lab = label[row];
  float2 v = make_float2(0.f, 0.f);
  if ((lab >> 1) == c2) { if (lab & 1) v.y = 1.f; else v.x = 1.f; }
  enc[t] = v;
}

// score[n][k] = 2*x_n.w_k - |w_k|^2 via MX-fp8 K=128 MFMA, 128x128 tile.
// T2 both-sides swizzle: LDS linear (global_load_lds), global SOURCE chunk
// pre-swizzled by (row&7), ds_read applies the same XOR (rule #21 involution).
// Raw s_barrier + manual waitcnt so next-tile stage loads fly under the MFMAs.
// pack = (orderable(score) << 32) | ~col  -> atomicMax == (max score, min col)
__global__ __launch_bounds__(256) void argmin_kernel(const unsigned char* __restrict__ Xq,
                                                     const unsigned char* __restrict__ Wq,
                                                     const float* __restrict__ wnorm,
                                                     unsigned long long* __restrict__ best) {
  constexpr int BKB = 128;   // k-bytes per step (fp8, K=128)
  __shared__ __attribute__((aligned(32))) unsigned char Asm[128 * BKB];  // 16 KB
  __shared__ __attribute__((aligned(32))) unsigned char Bsm[128 * BKB];  // 16 KB

  const int tid = threadIdx.x;
  const int w = tid >> 6, l = tid & 63;
  const int wr = w >> 1, wc = w & 1;
  const int lr = l & 15, lhk = l >> 4;
  const int r0 = blockIdx.x * 128;
  const int c0 = blockIdx.y * 128;

  // staging: thread t covers LDS row tid>>3 (+32 per issue), chunk tid&7 (16 B).
  // source chunk pre-swizzled: c ^ (row&7); (row&7) == ((tid>>3)&7) for all issues.
  const int srow = tid >> 3;
  const int scolb = (((tid & 7) ^ ((tid >> 3) & 7)) << 4);
  const unsigned char* gA = Xq + (size_t)(r0 + srow) * DP + scolb;
  const unsigned char* gB = Wq + (size_t)(c0 + srow) * DP + scolb;
  auto asA = (__attribute__((address_space(3))) unsigned char*)Asm;
  auto asB = (__attribute__((address_space(3))) unsigned char*)Bsm;
  const int wbase = w * 1024;              // bytes: wave's 64 lanes x 16B

  f32x4 zero = {0.f, 0.f, 0.f, 0.f};
  f32x4 acc[4][4];
  #pragma unroll
  for (int m = 0; m < 4; ++m)
    #pragma unroll
    for (int n = 0; n < 4; ++n) acc[m][n] = zero;

  // swizzled fragment LDS byte offsets: row r, k-chunks {2*lhk, 2*lhk+1} ^ (r&7)
  const int s = lr & 7;
  const int j0 = lhk * 2;
  int aoff_lo[4], aoff_hi[4], boff_lo[4], boff_hi[4];
  #pragma unroll
  for (int m = 0; m < 4; ++m) {
    const int ra = wr * 64 + m * 16 + lr;
    const int rb = wc * 64 + m * 16 + lr;
    aoff_lo[m] = ra * BKB + ((j0 ^ s) << 4);
    aoff_hi[m] = ra * BKB + (((j0 + 1) ^ s) << 4);
    boff_lo[m] = rb * BKB + ((j0 ^ s) << 4);
    boff_hi[m] = rb * BKB + (((j0 + 1) ^ s) << 4);
  }

  // prologue stage k0=0: 4 issues x (A,B), 32 rows per issue
  #pragma unroll
  for (int i = 0; i < 4; ++i) {
    __builtin_amdgcn_global_load_lds((gp_t)(gA + (size_t)(32 * i) * DP),
                                     (lp_t)(asA + i * 4096 + wbase), 16, 0, 0);
    __builtin_amdgcn_global_load_lds((gp_t)(gB + (size_t)(32 * i) * DP),
                                     (lp_t)(asB + i * 4096 + wbase), 16, 0, 0);
  }

  for (int k0 = 0; k0 < DP; k0 += BKB) {
    asm volatile("s_waitcnt vmcnt(0)" ::: "memory");  // my stage loads landed
    __builtin_amdgcn_s_barrier();                     // everyone's landed -> tile ready
    int8v a[4], b[4];
    #pragma unroll
    for (int m = 0; m < 4; ++m) {
      int4v alo = *reinterpret_cast<const int4v*>(Asm + aoff_lo[m]);
      int4v ahi = *reinterpret_cast<const int4v*>(Asm + aoff_hi[m]);
      int4v blo = *reinterpret_cast<const int4v*>(Bsm + boff_lo[m]);
      int4v bhi = *reinterpret_cast<const int4v*>(Bsm + boff_hi[m]);
      a[m][0] = alo[0]; a[m][1] = alo[1]; a[m][2] = alo[2]; a[m][3] = alo[3];
      a[m][4] = ahi[0]; a[m][5] = ahi[1]; a[m][6] = ahi[2]; a[m][7] = ahi[3];
      b[m][0] = blo[0]; b[m][1] = blo[1]; b[m][2] = blo[2]; b[m][3] = blo[3];
      b[m][4] = bhi[0]; b[m][5] = bhi[1]; b[m][6] = bhi[2]; b[m][7] = bhi[3];
    }
    asm volatile("s_waitcnt lgkmcnt(0)" ::: "memory"); // my ds_reads complete
    __builtin_amdgcn_s_barrier();                      // all waves done reading
    __builtin_amdgcn_sched_barrier(0);                 // pin stage issue here
    if (k0 + BKB < DP) {
      const int k1 = k0 + BKB;
      #pragma unroll
      for (int i = 0; i < 4; ++i) {
        __builtin_amdgcn_global_load_lds((gp_t)(gA + k1 + (size_t)(32 * i) * DP),
                                         (lp_t)(asA + i * 4096 + wbase), 16, 0, 0);
        __builtin_amdgcn_global_load_lds((gp_t)(gB + k1 + (size_t)(32 * i) * DP),
                                         (lp_t)(asB + i * 4096 + wbase), 16, 0, 0);
      }
    }
    #pragma unroll
    for (int m = 0; m < 4; ++m)
      #pragma unroll
      for (int n = 0; n < 4; ++n)
        acc[m][n] = __builtin_amdgcn_mfma_scale_f32_16x16x128_f8f6f4(
            a[m], b[n], acc[m][n], 0, 0, 0, 0x7f7f7f7f, 0, 0x7f7f7f7f);
  }

  // epilogue: scores + per-row argmax
  float wn[4];
  #pragma unroll
  for (int n = 0; n < 4; ++n) wn[n] = wnorm[c0 + wc * 64 + n * 16 + lr];
  const float dsc = 2.0f / WSCALE;

  #pragma unroll
  for (int m = 0; m < 4; ++m) {
    #pragma unroll
    for (int t = 0; t < 4; ++t) {
      const int row = r0 + wr * 64 + m * 16 + lhk * 4 + t;
      unsigned long long pk = 0ull;
      #pragma unroll
      for (int n = 0; n < 4; ++n) {
        const int col = c0 + wc * 64 + n * 16 + lr;
        float score = dsc * acc[m][n][t] - wn[n];
        unsigned int u = __float_as_uint(score);
        u = (u & 0x80000000u) ? ~u : (u | 0x80000000u);
        unsigned long long p = ((unsigned long long)u << 32) | (unsigned int)(~col);
        if (p > pk) pk = p;
      }
      #pragma unroll
      for (int off = 1; off < 16; off <<= 1) {
        unsigned long long o = __shfl_xor(pk, off);
        if (o > pk) pk = o;
      }
      if (lr == 0) atomicMax(best + row, pk);
    }
  }
}

// gather quantized rows, write straight-through output, per-block partial sums (NO atomics)
__global__ __launch_bounds__(256) void gather_loss_kernel(const float* __restrict__ X,
                                                          const float* __restrict__ W,
                                                          const int* __restrict__ label,
                                                          const unsigned long long* __restrict__ best,
                                                          float* __restrict__ outq,
                                                          float* __restrict__ partials) {
  const int tid = threadIdx.x;
  float qs = 0.f, xs = 0.f;
  #pragma unroll
  for (int i = 0; i < 8; ++i) {
    const int r = blockIdx.x * 8 + i;
    const int lab = label[r];
    const int k = (int)(~(unsigned int)(best[r] & 0xffffffffull));
    const float ind = (lab != k) ? 1.0f : 0.0f;
    if (tid < 250) {
      const float4 x4 = reinterpret_cast<const float4*>(X + (size_t)r * D)[tid];
      const float4 q4 = reinterpret_cast<const float4*>(W + (size_t)lab * D)[tid];
      const float4 c4 = reinterpret_cast<const float4*>(W + (size_t)k * D)[tid];
      float* orow = outq + (size_t)r * D + tid * 4;
      orow[0] = x4.x + (q4.x - x4.x);
      orow[1] = x4.y + (q4.y - x4.y);
      orow[2] = x4.z + (q4.z - x4.z);
      orow[3] = x4.w + (q4.w - x4.w);
      float dq, dc, rx = 0.f, rq = 0.f;
      dq = q4.x - x4.x; rq += dq * dq;  dq = q4.y - x4.y; rq += dq * dq;
      dq = q4.z - x4.z; rq += dq * dq;  dq = q4.w - x4.w; rq += dq * dq;
      dc = c4.x - x4.x; rx += dc * dc;  dc = c4.y - x4.y; rx += dc * dc;
      dc = c4.z - x4.z; rx += dc * dc;  dc = c4.w - x4.w; rx += dc * dc;
      qs += rq;
      xs += ind * rx;
    }
  }
  #pragma unroll
  for (int off = 32; off; off >>= 1) {
    qs += __shfl_down(qs, off);
    xs += __shfl_down(xs, off);
  }
  __shared__ float sq[4], sx[4];
  if ((tid & 63) == 0) { sq[tid >> 6] = qs; sx[tid >> 6] = xs; }
  __syncthreads();
  if (tid == 0) {
    partials[blockIdx.x * 2 + 0] = sq[0] + sq[1] + sq[2] + sq[3];
    partials[blockIdx.x * 2 + 1] = sx[0] + sx[1] + sx[2] + sx[3];
  }
}

__global__ __launch_bounds__(256) void final_kernel(const unsigned int* __restrict__ counts,
                                                    const float* __restrict__ partials,
                                                    float* __restrict__ out) {
  const int tid = threadIdx.x;
  float e = 0.f, qs = 0.f, xs = 0.f;
  for (int k = tid; k < K; k += 256) {
    float p = (float)counts[k] * (1.0f / (float)N);
    e += p * logf(p + 1e-10f);
  }
  for (int i = tid; i < 2048; i += 256) {
    qs += partials[i * 2 + 0];
    xs += partials[i * 2 + 1];
  }
  #pragma unroll
  for (int off = 32; off; off >>= 1) {
    e += __shfl_down(e, off);
    qs += __shfl_down(qs, off);
    xs += __shfl_down(xs, off);
  }
  __shared__ float se[4], ssq[4], ssx[4];
  if ((tid & 63) == 0) { se[tid >> 6] = e; ssq[tid >> 6] = qs; ssx[tid >> 6] = xs; }
  __syncthreads();
  if (tid == 0) {
    float ent = se[0] + se[1] + se[2] + se[3];
    float q = ssq[0] + ssq[1] + ssq[2] + ssq[3];
    float x = ssx[0] + ssx[1] + ssx[2] + ssx[3];
    const float inv = 1.0f / (float)((long long)N * D);
    out[0] = 1.25f * q * inv - 1.1f * x * inv;   // loss
    out[1 + ND] = expf(-ent);                    // perplexity
  }
}

extern "C" void kernel_launch(void* const* d_in, const int* in_sizes, int n_in,
                              void* d_out, int out_size, void* d_ws, size_t ws_size,
                              hipStream_t stream) {
  const float* X = (const float*)d_in[0];
  const int* label = (const int*)d_in[1];
  const float* W = (const float*)d_in[2];
  float* out = (float*)d_out;
  char* ws = (char*)d_ws;

  unsigned long long* best = (unsigned long long*)(ws + OFF_BEST);
  unsigned int* counts = (unsigned int*)(ws + OFF_COUNTS);
  float* partials = (float*)(ws + OFF_PART);
  unsigned char* Xq = (unsigned char*)(ws + OFF_XQ);
  unsigned char* Wq = (unsigned char*)(ws + OFF_WQ);
  float* wnorm = (float*)(ws + OFF_WNORM);

  // zero best+counts with a kernel (the graph-captured hipMemsetAsync fill
  // showed 113 us/dispatch in rocprof — either real cost or artifact; this
  // is ~2 us either way). 139264 B = 34 blocks * 256 threads * 16 B.
  init_kernel<<<34, 256, 0, stream>>>((uint4*)ws);

  conv_fp8_kernel<<<(N * 128) / 256, 256, 0, stream>>>(X, Xq, N, 1.0f);
  conv_fp8_kernel<<<(K * 128) / 256, 256, 0, stream>>>(W, Wq, K, WSCALE);
  wnorm_kernel<<<K / 4, 256, 0, stream>>>(W, wnorm);
  hist_kernel<<<N / 256, 256, 0, stream>>>(label, counts);
  encodings_kernel<<<(int)((size_t)N * K / 2 / 256), 256, 0, stream>>>(
      label, (float2*)(out + 2 + ND));
  argmin_kernel<<<dim3(N / 128, K / 128), 256, 0, stream>>>(Xq, Wq, wnorm, best);
  gather_loss_kernel<<<N / 8, 256, 0, stream>>>(X, W, label, best, out + 1, partials);
  final_kernel<<<1, 256, 0, stream>>>(counts, partials, out);
}